// Round 1
// baseline (562.878 us; speedup 1.0000x reference)
//
#include <hip/hip_runtime.h>
#include <hip/hip_bf16.h>

typedef __attribute__((ext_vector_type(8))) short short8;
typedef __attribute__((ext_vector_type(4))) float floatx4;

#define N_CELLS  500000
#define B_SAMP   512
#define D_X      128
#define D_Z      32
#define D_IN     160
#define H_DIM    256
#define D_OUT    16

#define M_TILE   32
#define LDA      168   // padded leading dim (bf16 elems) for Xp; 168*2B=336B=21*16B
#define LDH      264   // padded leading dim (bf16 elems) for h;  264*2B=528B=33*16B

// workspace layout (bytes); all 16B aligned
#define OFF_W1P   0           // 16 ntiles * 5 ksteps * 64 * 8 bf16 = 81920 B
#define OFF_W2P   81920       // 16 * 8 * 64 * 8 bf16 = 131072 B
#define OFF_W3P   212992      // 1 * 8 * 64 * 8 bf16 = 8192 B
#define OFF_XCELL 221184      // 500000*16*4 = 32000000 B
#define OFF_PART  32221184    // 256 * 8704 * 4 = 8912896 B  (total ~41.1 MB)
#define N_CHUNK   256
#define PART_STRIDE 8704      // 8192 sums + 512 counts (floats)

// Repack W[K][N] fp32 -> bf16 in MFMA B-fragment order:
// packed[((t*kS + s)*64 + L)*8 + j] = W[(s*32 + (L>>4)*8 + j)*N + t*16 + (L&15)]
__global__ void pack_w(const float* __restrict__ W, __hip_bfloat16* __restrict__ dst,
                       int N, int kS) {
    int idx = blockIdx.x * blockDim.x + threadIdx.x;
    int j = idx & 7;
    int L = (idx >> 3) & 63;
    int s = (idx >> 9) % kS;
    int t = idx / (kS << 9);
    int k = s * 32 + ((L >> 4) << 3) + j;
    int n = t * 16 + (L & 15);
    dst[idx] = __float2bfloat16(W[(size_t)k * N + n]);
}

__global__ __launch_bounds__(256, 3)
void fused_mlp(const float* __restrict__ X, const float* __restrict__ Z,
               const int* __restrict__ c2b,
               const float* __restrict__ b1, const float* __restrict__ b2,
               const float* __restrict__ b3,
               const __hip_bfloat16* __restrict__ w1p,
               const __hip_bfloat16* __restrict__ w2p,
               const __hip_bfloat16* __restrict__ w3p,
               float* __restrict__ xcell) {
    __shared__ __hip_bfloat16 sXp[M_TILE][LDA];
    __shared__ __hip_bfloat16 sH[2][M_TILE][LDH];
    __shared__ float sP[4][M_TILE][D_OUT];

    const int tid = threadIdx.x;
    const int w   = tid >> 6;    // wave 0..3
    const int L   = tid & 63;    // lane
    const int q   = L >> 4;      // quad 0..3
    const int ln  = L & 15;
    const int base = blockIdx.x * M_TILE;   // 500000 = 32*15625, no tail

    // ---- stage Xp = [log1p(X) | Z[c2b]] as bf16 into LDS ----
#pragma unroll
    for (int i = 0; i < 4; ++i) {
        int idx = tid + i * 256;          // 0..1023 = 32 rows * 32 float4
        int row = idx >> 5;
        int c4  = idx & 31;
        float4 v = *(const float4*)(X + (size_t)(base + row) * D_X + c4 * 4);
        __hip_bfloat16* d = &sXp[row][c4 * 4];
        d[0] = __float2bfloat16(__logf(1.0f + v.x));
        d[1] = __float2bfloat16(__logf(1.0f + v.y));
        d[2] = __float2bfloat16(__logf(1.0f + v.z));
        d[3] = __float2bfloat16(__logf(1.0f + v.w));
    }
    {
        int row = tid >> 3;               // 32 rows
        int c0  = (tid & 7) * 4;          // 8 float4-groups of D_Z=32
        int b   = c2b[base + row];
        float4 v = *(const float4*)(Z + (size_t)b * D_Z + c0);
        __hip_bfloat16* d = &sXp[row][D_X + c0];
        d[0] = __float2bfloat16(v.x);
        d[1] = __float2bfloat16(v.y);
        d[2] = __float2bfloat16(v.z);
        d[3] = __float2bfloat16(v.w);
    }
    __syncthreads();

    // ---- GEMM1: [32 x 160] @ [160 x 256] -> relu -> sH[0] ----
    floatx4 acc[2][4];
#pragma unroll
    for (int mt = 0; mt < 2; ++mt)
#pragma unroll
        for (int nt = 0; nt < 4; ++nt)
            acc[mt][nt] = (floatx4){0.f, 0.f, 0.f, 0.f};

    float bias1[4];
#pragma unroll
    for (int nt = 0; nt < 4; ++nt) bias1[nt] = b1[w * 64 + nt * 16 + ln];

#pragma unroll
    for (int s = 0; s < 5; ++s) {
        short8 a0 = *(const short8*)&sXp[ln][s * 32 + q * 8];
        short8 a1 = *(const short8*)&sXp[16 + ln][s * 32 + q * 8];
#pragma unroll
        for (int nt = 0; nt < 4; ++nt) {
            int t = w * 4 + nt;
            short8 bf = *(const short8*)(w1p + (size_t)(((t * 5 + s) << 6) + L) * 8);
            acc[0][nt] = __builtin_amdgcn_mfma_f32_16x16x32_bf16(a0, bf, acc[0][nt], 0, 0, 0);
            acc[1][nt] = __builtin_amdgcn_mfma_f32_16x16x32_bf16(a1, bf, acc[1][nt], 0, 0, 0);
        }
    }
#pragma unroll
    for (int mt = 0; mt < 2; ++mt)
#pragma unroll
        for (int nt = 0; nt < 4; ++nt)
#pragma unroll
            for (int r = 0; r < 4; ++r) {
                float v = fmaxf(acc[mt][nt][r] + bias1[nt], 0.0f);
                sH[0][mt * 16 + q * 4 + r][w * 64 + nt * 16 + ln] = __float2bfloat16(v);
            }
    __syncthreads();

    // ---- GEMM2: [32 x 256] @ [256 x 256] -> relu -> sH[1] ----
#pragma unroll
    for (int mt = 0; mt < 2; ++mt)
#pragma unroll
        for (int nt = 0; nt < 4; ++nt)
            acc[mt][nt] = (floatx4){0.f, 0.f, 0.f, 0.f};

    float bias2[4];
#pragma unroll
    for (int nt = 0; nt < 4; ++nt) bias2[nt] = b2[w * 64 + nt * 16 + ln];

#pragma unroll
    for (int s = 0; s < 8; ++s) {
        short8 a0 = *(const short8*)&sH[0][ln][s * 32 + q * 8];
        short8 a1 = *(const short8*)&sH[0][16 + ln][s * 32 + q * 8];
#pragma unroll
        for (int nt = 0; nt < 4; ++nt) {
            int t = w * 4 + nt;
            short8 bf = *(const short8*)(w2p + (size_t)(((t * 8 + s) << 6) + L) * 8);
            acc[0][nt] = __builtin_amdgcn_mfma_f32_16x16x32_bf16(a0, bf, acc[0][nt], 0, 0, 0);
            acc[1][nt] = __builtin_amdgcn_mfma_f32_16x16x32_bf16(a1, bf, acc[1][nt], 0, 0, 0);
        }
    }
#pragma unroll
    for (int mt = 0; mt < 2; ++mt)
#pragma unroll
        for (int nt = 0; nt < 4; ++nt)
#pragma unroll
            for (int r = 0; r < 4; ++r) {
                float v = fmaxf(acc[mt][nt][r] + bias2[nt], 0.0f);
                sH[1][mt * 16 + q * 4 + r][w * 64 + nt * 16 + ln] = __float2bfloat16(v);
            }
    __syncthreads();

    // ---- GEMM3: [32 x 256] @ [256 x 16], K split across 4 waves ----
    floatx4 acc3[2];
    acc3[0] = (floatx4){0.f, 0.f, 0.f, 0.f};
    acc3[1] = (floatx4){0.f, 0.f, 0.f, 0.f};
#pragma unroll
    for (int ss = 0; ss < 2; ++ss) {
        int s = w * 2 + ss;
        short8 a0 = *(const short8*)&sH[1][ln][s * 32 + q * 8];
        short8 a1 = *(const short8*)&sH[1][16 + ln][s * 32 + q * 8];
        short8 bf = *(const short8*)(w3p + (size_t)((s << 6) + L) * 8);
        acc3[0] = __builtin_amdgcn_mfma_f32_16x16x32_bf16(a0, bf, acc3[0], 0, 0, 0);
        acc3[1] = __builtin_amdgcn_mfma_f32_16x16x32_bf16(a1, bf, acc3[1], 0, 0, 0);
    }
#pragma unroll
    for (int mt = 0; mt < 2; ++mt)
#pragma unroll
        for (int r = 0; r < 4; ++r)
            sP[w][mt * 16 + q * 4 + r][ln] = acc3[mt][r];
    __syncthreads();

    // combine wave partials + b3, store X_cell (coalesced)
#pragma unroll
    for (int i = 0; i < 2; ++i) {
        int idx = tid + i * 256;   // 0..511 = 32 cells * 16 outs
        int m = idx >> 4, n = idx & 15;
        float v = sP[0][m][n] + sP[1][m][n] + sP[2][m][n] + sP[3][m][n] + b3[n];
        xcell[(size_t)(base + m) * D_OUT + n] = v;
    }
}

// Segment reduce: each block accumulates a chunk of cells into an LDS [512][16]
// accumulator (+counts), writes deterministic partials to ws (no global atomics).
__global__ __launch_bounds__(256)
void reduce_seg(const float* __restrict__ xcell, const int* __restrict__ c2b,
                const int* __restrict__ sidx, float* __restrict__ part) {
    __shared__ float ls[B_SAMP * D_OUT];
    __shared__ float lc[B_SAMP];
    const int tid = threadIdx.x;
    for (int i = tid; i < B_SAMP * D_OUT; i += 256) ls[i] = 0.f;
    for (int i = tid; i < B_SAMP; i += 256) lc[i] = 0.f;
    __syncthreads();

    const int cpc = (N_CELLS + N_CHUNK - 1) / N_CHUNK;   // 1954
    const int start = blockIdx.x * cpc;
    const int end = min(start + cpc, N_CELLS);
    const int ci = tid >> 4;    // 16 cells in flight
    const int n  = tid & 15;
    for (int c = start + ci; c < end; c += 16) {
        int b = c2b[c];
        int s = sidx[b] & (B_SAMP - 1);
        float v = xcell[(size_t)c * D_OUT + n];
        atomicAdd(&ls[s * D_OUT + n], v);
        if (n == 0) atomicAdd(&lc[s], 1.0f);
    }
    __syncthreads();

    float* dst = part + (size_t)blockIdx.x * PART_STRIDE;
    for (int i = tid; i < B_SAMP * D_OUT; i += 256) dst[i] = ls[i];
    for (int i = tid; i < B_SAMP; i += 256) dst[B_SAMP * D_OUT + i] = lc[i];
}

__global__ __launch_bounds__(256)
void finalize(const float* __restrict__ part, float* __restrict__ out) {
    int o = blockIdx.x * blockDim.x + threadIdx.x;   // 0..8191
    int s = o >> 4;
    float sum = 0.f, cnt = 0.f;
    for (int c = 0; c < N_CHUNK; ++c) {
        sum += part[(size_t)c * PART_STRIDE + o];
        cnt += part[(size_t)c * PART_STRIDE + B_SAMP * D_OUT + s];
    }
    out[o] = sum / fmaxf(cnt, 1.0f);
}

extern "C" void kernel_launch(void* const* d_in, const int* in_sizes, int n_in,
                              void* d_out, int out_size, void* d_ws, size_t ws_size,
                              hipStream_t stream) {
    const float* X   = (const float*)d_in[0];
    const float* Z   = (const float*)d_in[1];
    const float* W1  = (const float*)d_in[2];
    const float* b1  = (const float*)d_in[3];
    const float* W2  = (const float*)d_in[4];
    const float* b2  = (const float*)d_in[5];
    const float* W3  = (const float*)d_in[6];
    const float* b3  = (const float*)d_in[7];
    const int*   c2b = (const int*)d_in[8];
    const int*   sidx= (const int*)d_in[9];

    char* ws = (char*)d_ws;
    __hip_bfloat16* w1p = (__hip_bfloat16*)(ws + OFF_W1P);
    __hip_bfloat16* w2p = (__hip_bfloat16*)(ws + OFF_W2P);
    __hip_bfloat16* w3p = (__hip_bfloat16*)(ws + OFF_W3P);
    float* xcell = (float*)(ws + OFF_XCELL);
    float* part  = (float*)(ws + OFF_PART);
    float* out   = (float*)d_out;

    // repack weights to bf16 MFMA B-fragment layout (same work every call)
    pack_w<<<160, 256, 0, stream>>>(W1, w1p, H_DIM, 5);   // 16*5*512 threads
    pack_w<<<256, 256, 0, stream>>>(W2, w2p, H_DIM, 8);   // 16*8*512
    pack_w<<<16,  256, 0, stream>>>(W3, w3p, D_OUT, 8);   // 1*8*512

    fused_mlp<<<N_CELLS / M_TILE, 256, 0, stream>>>(X, Z, c2b, b1, b2, b3,
                                                    w1p, w2p, w3p, xcell);
    reduce_seg<<<N_CHUNK, 256, 0, stream>>>(xcell, c2b, sidx, part);
    finalize<<<32, 256, 0, stream>>>(part, out);
}

// Round 2
// 510.623 us; speedup vs baseline: 1.1023x; 1.1023x over previous
//
#include <hip/hip_runtime.h>
#include <hip/hip_bf16.h>

typedef __attribute__((ext_vector_type(8))) short short8;
typedef __attribute__((ext_vector_type(4))) float floatx4;

#define N_CELLS  500000
#define B_SAMP   512
#define D_X      128
#define D_Z      32
#define D_IN     160
#define H_DIM    256
#define D_OUT    16

#define M_TILE   32
#define LDA      168   // padded leading dim (bf16 elems) for Xp
#define LDH      264   // padded leading dim (bf16 elems) for h

#define NREP     64    // accumulator replicas to spread atomic contention

// workspace layout (bytes); all 16B aligned
#define OFF_W1P   0           // 16 ntiles * 5 ksteps * 64 * 8 bf16 = 81920 B
#define OFF_W2P   81920       // 16 * 8 * 64 * 8 bf16 = 131072 B
#define OFF_W3P   212992      // 1 * 8 * 64 * 8 bf16 = 8192 B
#define OFF_ACC   221184      // NREP * 8192 * 4 = 2097152 B
#define OFF_CNT   2318336     // NREP * 512 * 4  = 131072 B   (total ~2.45 MB)

// Repack W[K][N] fp32 -> bf16 in MFMA B-fragment order:
// packed[((t*kS + s)*64 + L)*8 + j] = W[(s*32 + (L>>4)*8 + j)*N + t*16 + (L&15)]
__global__ void pack_w(const float* __restrict__ W, __hip_bfloat16* __restrict__ dst,
                       int N, int kS) {
    int idx = blockIdx.x * blockDim.x + threadIdx.x;
    int j = idx & 7;
    int L = (idx >> 3) & 63;
    int s = (idx >> 9) % kS;
    int t = idx / (kS << 9);
    int k = s * 32 + ((L >> 4) << 3) + j;
    int n = t * 16 + (L & 15);
    dst[idx] = __float2bfloat16(W[(size_t)k * N + n]);
}

__global__ void zero_ws(float* __restrict__ p, int n) {
    int i = blockIdx.x * blockDim.x + threadIdx.x;
    if (i < n) p[i] = 0.0f;
}

__global__ __launch_bounds__(256, 3)
void fused_mlp(const float* __restrict__ X, const float* __restrict__ Z,
               const int* __restrict__ c2b, const int* __restrict__ sidx,
               const float* __restrict__ b1, const float* __restrict__ b2,
               const float* __restrict__ b3,
               const __hip_bfloat16* __restrict__ w1p,
               const __hip_bfloat16* __restrict__ w2p,
               const __hip_bfloat16* __restrict__ w3p,
               float* __restrict__ accs, float* __restrict__ cnts) {
    __shared__ __hip_bfloat16 sXp[M_TILE][LDA];
    __shared__ __hip_bfloat16 sH[2][M_TILE][LDH];
    __shared__ float sP[4][M_TILE][D_OUT];

    const int tid = threadIdx.x;
    const int w   = tid >> 6;    // wave 0..3
    const int L   = tid & 63;    // lane
    const int q   = L >> 4;      // quad 0..3
    const int ln  = L & 15;
    const int base = blockIdx.x * M_TILE;   // 500000 = 32*15625, no tail

    // ---- stage Xp = [log1p(X) | Z[c2b]] as bf16 into LDS ----
#pragma unroll
    for (int i = 0; i < 4; ++i) {
        int idx = tid + i * 256;          // 0..1023 = 32 rows * 32 float4
        int row = idx >> 5;
        int c4  = idx & 31;
        float4 v = *(const float4*)(X + (size_t)(base + row) * D_X + c4 * 4);
        __hip_bfloat16* d = &sXp[row][c4 * 4];
        d[0] = __float2bfloat16(__logf(1.0f + v.x));
        d[1] = __float2bfloat16(__logf(1.0f + v.y));
        d[2] = __float2bfloat16(__logf(1.0f + v.z));
        d[3] = __float2bfloat16(__logf(1.0f + v.w));
    }
    {
        int row = tid >> 3;               // 32 rows
        int c0  = (tid & 7) * 4;          // 8 float4-groups of D_Z=32
        int b   = c2b[base + row];
        float4 v = *(const float4*)(Z + (size_t)b * D_Z + c0);
        __hip_bfloat16* d = &sXp[row][D_X + c0];
        d[0] = __float2bfloat16(v.x);
        d[1] = __float2bfloat16(v.y);
        d[2] = __float2bfloat16(v.z);
        d[3] = __float2bfloat16(v.w);
    }
    __syncthreads();

    // ---- GEMM1: [32 x 160] @ [160 x 256] -> relu -> sH[0] ----
    floatx4 acc[2][4];
#pragma unroll
    for (int mt = 0; mt < 2; ++mt)
#pragma unroll
        for (int nt = 0; nt < 4; ++nt)
            acc[mt][nt] = (floatx4){0.f, 0.f, 0.f, 0.f};

    float bias1[4];
#pragma unroll
    for (int nt = 0; nt < 4; ++nt) bias1[nt] = b1[w * 64 + nt * 16 + ln];

#pragma unroll
    for (int s = 0; s < 5; ++s) {
        short8 a0 = *(const short8*)&sXp[ln][s * 32 + q * 8];
        short8 a1 = *(const short8*)&sXp[16 + ln][s * 32 + q * 8];
#pragma unroll
        for (int nt = 0; nt < 4; ++nt) {
            int t = w * 4 + nt;
            short8 bf = *(const short8*)(w1p + (size_t)(((t * 5 + s) << 6) + L) * 8);
            acc[0][nt] = __builtin_amdgcn_mfma_f32_16x16x32_bf16(a0, bf, acc[0][nt], 0, 0, 0);
            acc[1][nt] = __builtin_amdgcn_mfma_f32_16x16x32_bf16(a1, bf, acc[1][nt], 0, 0, 0);
        }
    }
#pragma unroll
    for (int mt = 0; mt < 2; ++mt)
#pragma unroll
        for (int nt = 0; nt < 4; ++nt)
#pragma unroll
            for (int r = 0; r < 4; ++r) {
                float v = fmaxf(acc[mt][nt][r] + bias1[nt], 0.0f);
                sH[0][mt * 16 + q * 4 + r][w * 64 + nt * 16 + ln] = __float2bfloat16(v);
            }
    __syncthreads();

    // ---- GEMM2: [32 x 256] @ [256 x 256] -> relu -> sH[1] ----
#pragma unroll
    for (int mt = 0; mt < 2; ++mt)
#pragma unroll
        for (int nt = 0; nt < 4; ++nt)
            acc[mt][nt] = (floatx4){0.f, 0.f, 0.f, 0.f};

    float bias2[4];
#pragma unroll
    for (int nt = 0; nt < 4; ++nt) bias2[nt] = b2[w * 64 + nt * 16 + ln];

#pragma unroll
    for (int s = 0; s < 8; ++s) {
        short8 a0 = *(const short8*)&sH[0][ln][s * 32 + q * 8];
        short8 a1 = *(const short8*)&sH[0][16 + ln][s * 32 + q * 8];
#pragma unroll
        for (int nt = 0; nt < 4; ++nt) {
            int t = w * 4 + nt;
            short8 bf = *(const short8*)(w2p + (size_t)(((t * 8 + s) << 6) + L) * 8);
            acc[0][nt] = __builtin_amdgcn_mfma_f32_16x16x32_bf16(a0, bf, acc[0][nt], 0, 0, 0);
            acc[1][nt] = __builtin_amdgcn_mfma_f32_16x16x32_bf16(a1, bf, acc[1][nt], 0, 0, 0);
        }
    }
#pragma unroll
    for (int mt = 0; mt < 2; ++mt)
#pragma unroll
        for (int nt = 0; nt < 4; ++nt)
#pragma unroll
            for (int r = 0; r < 4; ++r) {
                float v = fmaxf(acc[mt][nt][r] + bias2[nt], 0.0f);
                sH[1][mt * 16 + q * 4 + r][w * 64 + nt * 16 + ln] = __float2bfloat16(v);
            }
    __syncthreads();

    // ---- GEMM3: [32 x 256] @ [256 x 16], K split across 4 waves ----
    floatx4 acc3[2];
    acc3[0] = (floatx4){0.f, 0.f, 0.f, 0.f};
    acc3[1] = (floatx4){0.f, 0.f, 0.f, 0.f};
#pragma unroll
    for (int ss = 0; ss < 2; ++ss) {
        int s = w * 2 + ss;
        short8 a0 = *(const short8*)&sH[1][ln][s * 32 + q * 8];
        short8 a1 = *(const short8*)&sH[1][16 + ln][s * 32 + q * 8];
        short8 bf = *(const short8*)(w3p + (size_t)((s << 6) + L) * 8);
        acc3[0] = __builtin_amdgcn_mfma_f32_16x16x32_bf16(a0, bf, acc3[0], 0, 0, 0);
        acc3[1] = __builtin_amdgcn_mfma_f32_16x16x32_bf16(a1, bf, acc3[1], 0, 0, 0);
    }
#pragma unroll
    for (int mt = 0; mt < 2; ++mt)
#pragma unroll
        for (int r = 0; r < 4; ++r)
            sP[w][mt * 16 + q * 4 + r][ln] = acc3[mt][r];
    __syncthreads();

    // ---- fused epilogue: combine wave partials + b3, atomic segment-sum ----
    float* accR = accs + (size_t)(blockIdx.x & (NREP - 1)) * (B_SAMP * D_OUT);
    float* cntR = cnts + (size_t)(blockIdx.x & (NREP - 1)) * B_SAMP;
#pragma unroll
    for (int i = 0; i < 2; ++i) {
        int idx = tid + i * 256;   // 0..511 = 32 cells * 16 outs
        int m = idx >> 4, n = idx & 15;
        float v = sP[0][m][n] + sP[1][m][n] + sP[2][m][n] + sP[3][m][n] + b3[n];
        int b = c2b[base + m];
        int s = sidx[b];
        atomicAdd(&accR[(size_t)s * D_OUT + n], v);
        if (n == 0) atomicAdd(&cntR[s], 1.0f);
    }
}

__global__ __launch_bounds__(256)
void finalize(const float* __restrict__ accs, const float* __restrict__ cnts,
              float* __restrict__ out) {
    int o = blockIdx.x * blockDim.x + threadIdx.x;   // 0..8191
    int s = o >> 4;
    float sum = 0.f, cnt = 0.f;
#pragma unroll 8
    for (int r = 0; r < NREP; ++r) {
        sum += accs[(size_t)r * (B_SAMP * D_OUT) + o];
        cnt += cnts[(size_t)r * B_SAMP + s];
    }
    out[o] = sum / fmaxf(cnt, 1.0f);
}

extern "C" void kernel_launch(void* const* d_in, const int* in_sizes, int n_in,
                              void* d_out, int out_size, void* d_ws, size_t ws_size,
                              hipStream_t stream) {
    const float* X   = (const float*)d_in[0];
    const float* Z   = (const float*)d_in[1];
    const float* W1  = (const float*)d_in[2];
    const float* b1  = (const float*)d_in[3];
    const float* W2  = (const float*)d_in[4];
    const float* b2  = (const float*)d_in[5];
    const float* W3  = (const float*)d_in[6];
    const float* b3  = (const float*)d_in[7];
    const int*   c2b = (const int*)d_in[8];
    const int*   sidx= (const int*)d_in[9];

    char* ws = (char*)d_ws;
    __hip_bfloat16* w1p = (__hip_bfloat16*)(ws + OFF_W1P);
    __hip_bfloat16* w2p = (__hip_bfloat16*)(ws + OFF_W2P);
    __hip_bfloat16* w3p = (__hip_bfloat16*)(ws + OFF_W3P);
    float* accs = (float*)(ws + OFF_ACC);
    float* cnts = (float*)(ws + OFF_CNT);
    float* out  = (float*)d_out;

    // zero the replicated accumulators (ws is re-poisoned before every call)
    {
        int nz = NREP * (B_SAMP * D_OUT + B_SAMP);   // 557056 floats
        zero_ws<<<(nz + 255) / 256, 256, 0, stream>>>(accs, nz);
    }

    // repack weights to bf16 MFMA B-fragment layout (same work every call)
    pack_w<<<160, 256, 0, stream>>>(W1, w1p, H_DIM, 5);   // 16*5*512 threads
    pack_w<<<256, 256, 0, stream>>>(W2, w2p, H_DIM, 8);   // 16*8*512
    pack_w<<<16,  256, 0, stream>>>(W3, w3p, D_OUT, 8);   // 1*8*512

    fused_mlp<<<N_CELLS / M_TILE, 256, 0, stream>>>(X, Z, c2b, sidx, b1, b2, b3,
                                                    w1p, w2p, w3p, accs, cnts);
    finalize<<<32, 256, 0, stream>>>(accs, cnts, out);
}